// Round 1
// baseline (1107.275 us; speedup 1.0000x reference)
//
#include <hip/hip_runtime.h>
#include <hip/hip_bf16.h>
#include <math.h>

#define XW 4099
#define DSD 3
#define BSZ 8192

// ---------------------------------------------------------------------------
// Kernel 1: fused conv1+relu+pool -> conv2+relu+pool -> act1[b][1693]
// One block (256 threads) per image.
// ---------------------------------------------------------------------------
__global__ __launch_bounds__(256) void conv_fused(
    const float* __restrict__ x,
    const float* __restrict__ w1, const float* __restrict__ b1,
    const float* __restrict__ w2, const float* __restrict__ b2,
    float* __restrict__ act1)
{
    __shared__ float img[64 * 64];      // 16 KB
    __shared__ float h1[5 * 30 * 30];   // 18 KB
    __shared__ float cw2[10 * 5 * 25];  // 5 KB
    __shared__ float cb2[10];
    __shared__ float cw1[5 * 25];
    __shared__ float cb1[5];

    const int b = blockIdx.x;
    const int t = threadIdx.x;

    const float* xr = x + (size_t)b * XW + DSD;
    for (int i = t; i < 4096; i += 256) img[i] = xr[i];
    for (int i = t; i < 125;  i += 256) cw1[i] = w1[i];
    for (int i = t; i < 1250; i += 256) cw2[i] = w2[i];
    if (t < 5)  cb1[t] = b1[t];
    if (t < 10) cb2[t] = b2[t];
    __syncthreads();

    // conv1 + relu + 2x2 maxpool -> h1[5][30][30]
    for (int idx = t; idx < 5 * 30 * 30; idx += 256) {
        const int c  = idx / 900;
        const int r  = idx % 900;
        const int py = r / 30, px = r % 30;
        // weights into registers: one LDS read per 4 FMAs below
        float wr[25];
        #pragma unroll
        for (int i = 0; i < 25; ++i) wr[i] = cw1[c * 25 + i];
        const float bias = cb1[c];
        float a00 = bias, a01 = bias, a10 = bias, a11 = bias;
        const int y0 = py * 2, x0 = px * 2;
        #pragma unroll
        for (int ky = 0; ky < 5; ++ky) {
            #pragma unroll
            for (int kx = 0; kx < 5; ++kx) {
                const float w = wr[ky * 5 + kx];
                const float* ip = img + (y0 + ky) * 64 + (x0 + kx);
                a00 += ip[0] * w;
                a01 += ip[1] * w;
                a10 += ip[64] * w;
                a11 += ip[65] * w;
            }
        }
        a00 = fmaxf(a00, 0.f); a01 = fmaxf(a01, 0.f);
        a10 = fmaxf(a10, 0.f); a11 = fmaxf(a11, 0.f);
        h1[idx] = fmaxf(fmaxf(a00, a01), fmaxf(a10, a11));
    }
    __syncthreads();

    // conv2 + relu + 2x2 maxpool -> act1[b][c*169 + py*13 + px]
    float* out = act1 + (size_t)b * 1693;
    for (int idx = t; idx < 10 * 13 * 13; idx += 256) {
        const int o  = idx / 169;
        const int r  = idx % 169;
        const int py = r / 13, px = r % 13;
        const float bias = cb2[o];
        float a00 = bias, a01 = bias, a10 = bias, a11 = bias;
        const int y0 = py * 2, x0 = px * 2;
        for (int i = 0; i < 5; ++i) {
            const float* wo = cw2 + (o * 5 + i) * 25;
            const float* hp = h1 + i * 900 + y0 * 30 + x0;
            #pragma unroll
            for (int ky = 0; ky < 5; ++ky) {
                #pragma unroll
                for (int kx = 0; kx < 5; ++kx) {
                    const float w = wo[ky * 5 + kx];      // 1 LDS read
                    const float* ip = hp + ky * 30 + kx;  // 4 LDS reads
                    a00 += ip[0] * w;
                    a01 += ip[1] * w;
                    a10 += ip[30] * w;
                    a11 += ip[31] * w;
                }
            }
        }
        a00 = fmaxf(a00, 0.f); a01 = fmaxf(a01, 0.f);
        a10 = fmaxf(a10, 0.f); a11 = fmaxf(a11, 0.f);
        out[idx] = fmaxf(fmaxf(a00, a01), fmaxf(a10, a11));
    }
    // concat the DS_DIM state dims after the 1690 conv features
    if (t < DSD) out[1690 + t] = x[(size_t)b * XW + t];
}

// ---------------------------------------------------------------------------
// Kernel 2: generic f32 GEMM  C[M,N] = relu(A[M,K] @ W[N,K]^T + bias)
// 64x64 tile, BK=16, 256 threads, 4x4 micro-tile per thread.
// ---------------------------------------------------------------------------
template <int RELU>
__global__ __launch_bounds__(256) void gemm_relu(
    const float* __restrict__ A,     // [M,K]
    const float* __restrict__ W,     // [N,K]
    const float* __restrict__ bias,  // [N]
    float* __restrict__ C,           // [M,N]
    int M, int N, int K)
{
    constexpr int BM = 64, BN = 64, BK = 16;
    __shared__ float As[BK][BM + 1];
    __shared__ float Ws[BK][BN + 1];

    const int tid = threadIdx.x;
    const int tx = tid % 16, ty = tid / 16;
    const int m0 = blockIdx.y * BM;
    const int n0 = blockIdx.x * BN;

    float acc[4][4] = {};

    for (int k0 = 0; k0 < K; k0 += BK) {
        for (int i = tid; i < BM * BK; i += 256) {
            const int mm = i / BK, kk = i % BK;
            const int k = k0 + kk;
            As[kk][mm] = (k < K) ? A[(size_t)(m0 + mm) * K + k] : 0.f;
        }
        for (int i = tid; i < BN * BK; i += 256) {
            const int nn = i / BK, kk = i % BK;
            const int k = k0 + kk;
            Ws[kk][nn] = (k < K) ? W[(size_t)(n0 + nn) * K + k] : 0.f;
        }
        __syncthreads();
        #pragma unroll
        for (int kk = 0; kk < BK; ++kk) {
            float a[4], w[4];
            #pragma unroll
            for (int i = 0; i < 4; ++i) a[i] = As[kk][ty * 4 + i];
            #pragma unroll
            for (int j = 0; j < 4; ++j) w[j] = Ws[kk][tx * 4 + j];
            #pragma unroll
            for (int i = 0; i < 4; ++i)
                #pragma unroll
                for (int j = 0; j < 4; ++j)
                    acc[i][j] += a[i] * w[j];
        }
        __syncthreads();
    }

    #pragma unroll
    for (int i = 0; i < 4; ++i) {
        const int m = m0 + ty * 4 + i;
        #pragma unroll
        for (int j = 0; j < 4; ++j) {
            const int n = n0 + tx * 4 + j;
            float v = acc[i][j] + bias[n];
            if (RELU) v = fmaxf(v, 0.f);
            C[(size_t)m * N + n] = v;
        }
    }
}

// ---------------------------------------------------------------------------
// Kernel 3: fc5 (64->16) + softmax + mixture-of-experts combine -> out[B,3]
// One thread per batch row.
// ---------------------------------------------------------------------------
__global__ __launch_bounds__(256) void head_kernel(
    const float* __restrict__ act5,  // [B,64]
    const float* __restrict__ w5,    // [16,64]
    const float* __restrict__ b5,    // [16]
    const float* __restrict__ Bm,    // [16,9]
    const float* __restrict__ Cm,    // [16,9]
    const float* __restrict__ x,     // [B,4099]
    const float* __restrict__ x_tar, // [1,3]
    float* __restrict__ out)         // [B,3]
{
    __shared__ float sw[16 * 64];
    __shared__ float sb[16];
    __shared__ float sA[16 * 9];
    __shared__ float st[3];
    const int t = threadIdx.x;
    for (int i = t; i < 1024; i += 256) sw[i] = w5[i];
    if (t < 16)  sb[t] = b5[t];
    if (t < 144) sA[t] = Bm[t] + Cm[t];
    if (t < 3)   st[t] = x_tar[t];
    __syncthreads();

    const int b = blockIdx.x * 256 + t;
    float h[64];
    const float* ar = act5 + (size_t)b * 64;
    #pragma unroll
    for (int i = 0; i < 64; ++i) h[i] = ar[i];

    float logit[16];
    float mx = -1e30f;
    #pragma unroll
    for (int n = 0; n < 16; ++n) {
        float s = sb[n];
        const float* wr = sw + n * 64;
        #pragma unroll
        for (int i = 0; i < 64; ++i) s += h[i] * wr[i];
        logit[n] = s;
        mx = fmaxf(mx, s);
    }
    float sum = 0.f;
    #pragma unroll
    for (int n = 0; n < 16; ++n) { logit[n] = __expf(logit[n] - mx); sum += logit[n]; }
    const float inv = 1.f / sum;

    const float d0 = st[0] - x[(size_t)b * XW + 0];
    const float d1 = st[1] - x[(size_t)b * XW + 1];
    const float d2 = st[2] - x[(size_t)b * XW + 2];
    float s0 = 0.f, s1 = 0.f, s2 = 0.f;
    #pragma unroll
    for (int n = 0; n < 16; ++n) {
        const float w = logit[n] * inv;
        const float* An = sA + n * 9;
        s0 += w * (An[0] * d0 + An[1] * d1 + An[2] * d2);
        s1 += w * (An[3] * d0 + An[4] * d1 + An[5] * d2);
        s2 += w * (An[6] * d0 + An[7] * d1 + An[8] * d2);
    }
    out[(size_t)b * 3 + 0] = s0;
    out[(size_t)b * 3 + 1] = s1;
    out[(size_t)b * 3 + 2] = s2;
}

// ---------------------------------------------------------------------------
extern "C" void kernel_launch(void* const* d_in, const int* in_sizes, int n_in,
                              void* d_out, int out_size, void* d_ws, size_t ws_size,
                              hipStream_t stream) {
    const float* x       = (const float*)d_in[0];
    const float* conv1_w = (const float*)d_in[1];
    const float* conv1_b = (const float*)d_in[2];
    const float* conv2_w = (const float*)d_in[3];
    const float* conv2_b = (const float*)d_in[4];
    const float* fc1_w   = (const float*)d_in[5];
    const float* fc1_b   = (const float*)d_in[6];
    const float* fc2_w   = (const float*)d_in[7];
    const float* fc2_b   = (const float*)d_in[8];
    const float* fc3_w   = (const float*)d_in[9];
    const float* fc3_b   = (const float*)d_in[10];
    const float* fc4_w   = (const float*)d_in[11];
    const float* fc4_b   = (const float*)d_in[12];
    const float* fc5_w   = (const float*)d_in[13];
    const float* fc5_b   = (const float*)d_in[14];
    const float* B_mats  = (const float*)d_in[15];
    const float* C_mats  = (const float*)d_in[16];
    const float* x_tar   = (const float*)d_in[17];
    float* out = (float*)d_out;

    float* ws   = (float*)d_ws;
    float* act1 = ws;                                   // [8192,1693]
    float* act2 = act1 + (size_t)BSZ * 1693;            // [8192,512]
    float* act3 = act2 + (size_t)BSZ * 512;             // [8192,256]
    float* act4 = act3 + (size_t)BSZ * 256;             // [8192,128]
    float* act5 = act4 + (size_t)BSZ * 128;             // [8192,64]

    conv_fused<<<BSZ, 256, 0, stream>>>(x, conv1_w, conv1_b, conv2_w, conv2_b, act1);

    gemm_relu<1><<<dim3(512 / 64, BSZ / 64), 256, 0, stream>>>(act1, fc1_w, fc1_b, act2, BSZ, 512, 1693);
    gemm_relu<1><<<dim3(256 / 64, BSZ / 64), 256, 0, stream>>>(act2, fc2_w, fc2_b, act3, BSZ, 256, 512);
    gemm_relu<1><<<dim3(128 / 64, BSZ / 64), 256, 0, stream>>>(act3, fc3_w, fc3_b, act4, BSZ, 128, 256);
    gemm_relu<1><<<dim3(64 / 64,  BSZ / 64), 256, 0, stream>>>(act4, fc4_w, fc4_b, act5, BSZ, 64, 128);

    head_kernel<<<BSZ / 256, 256, 0, stream>>>(act5, fc5_w, fc5_b, B_mats, C_mats, x, x_tar, out);
}

// Round 2
// 676.014 us; speedup vs baseline: 1.6379x; 1.6379x over previous
//
#include <hip/hip_runtime.h>
#include <hip/hip_bf16.h>
#include <hip/hip_fp16.h>
#include <math.h>

#define XW 4099
#define DSD 3
#define BSZ 8192
#define KP1 1696   // fc1 K padded: 1693 -> 1696 (multiple of 32, 16B-aligned rows)

typedef __attribute__((ext_vector_type(8))) _Float16 f16x8;
typedef __attribute__((ext_vector_type(4))) float    f32x4;

static __device__ __forceinline__ short f2h(float f) {
    union { _Float16 h; short s; } u;
    u.h = (_Float16)f;
    return u.s;
}

// ---------------------------------------------------------------------------
// Kernel 0: f32 -> f16 weight conversion with K-padding.  dst[N][Kp]
// ---------------------------------------------------------------------------
__global__ __launch_bounds__(256) void cvt_f16_pad(
    const float* __restrict__ src, short* __restrict__ dst,
    int N, int K, int Kp)
{
    const int tot = N * Kp;
    for (int i = blockIdx.x * 256 + threadIdx.x; i < tot; i += gridDim.x * 256) {
        const int n = i / Kp, k = i % Kp;
        dst[i] = (k < K) ? f2h(src[(size_t)n * K + k]) : (short)0;
    }
}

// ---------------------------------------------------------------------------
// Kernel 1: fused conv1+relu+pool -> conv2+relu+pool -> act1[b][1696] (f16)
// One block (256 threads) per image. Register-patch loads (float2) so each
// 6x6 window is read once per 100 FMAs; weights live in registers.
// ---------------------------------------------------------------------------
__global__ __launch_bounds__(256) void conv_fused(
    const float* __restrict__ x,
    const float* __restrict__ w1, const float* __restrict__ b1,
    const float* __restrict__ w2, const float* __restrict__ b2,
    short* __restrict__ act1)
{
    __shared__ float img[64 * 64];      // 16 KB
    __shared__ float h1[5][30][30];     // 18 KB
    __shared__ float cw1[125], cw2[1250];
    __shared__ float cb1[5], cb2[10];

    const int b = blockIdx.x;
    const int t = threadIdx.x;

    const float* xr = x + (size_t)b * XW + DSD;
    #pragma unroll
    for (int i = 0; i < 16; ++i) img[t + 256 * i] = xr[t + 256 * i];
    for (int i = t; i < 125;  i += 256) cw1[i] = w1[i];
    for (int i = t; i < 1250; i += 256) cw2[i] = w2[i];
    if (t < 5)  cb1[t] = b1[t];
    if (t < 10) cb2[t] = b2[t];
    __syncthreads();

    // ---- conv1 + relu + 2x2 pool -> h1[c][30][30]
    // threads 0..249: c = t/50, 50 lanes cover 900 spatial in 18 steps (exact)
    if (t < 250) {
        const int c = t / 50, j = t % 50;
        float wr[25];
        #pragma unroll
        for (int i = 0; i < 25; ++i) wr[i] = cw1[c * 25 + i];  // LDS broadcast
        const float bias = cb1[c];
        for (int s = 0; s < 18; ++s) {
            const int r  = s * 50 + j;          // 0..899
            const int py = r / 30, px = r % 30;
            const int y0 = py * 2, x0 = px * 2; // even -> float2 aligned
            float p[6][6];
            #pragma unroll
            for (int ky = 0; ky < 6; ++ky) {
                const float2* ip = (const float2*)&img[(y0 + ky) * 64 + x0];
                const float2 v0 = ip[0], v1 = ip[1], v2 = ip[2];
                p[ky][0] = v0.x; p[ky][1] = v0.y; p[ky][2] = v1.x;
                p[ky][3] = v1.y; p[ky][4] = v2.x; p[ky][5] = v2.y;
            }
            float a00 = bias, a01 = bias, a10 = bias, a11 = bias;
            #pragma unroll
            for (int ky = 0; ky < 5; ++ky)
                #pragma unroll
                for (int kx = 0; kx < 5; ++kx) {
                    const float w = wr[ky * 5 + kx];
                    a00 += p[ky][kx]     * w;
                    a01 += p[ky][kx + 1] * w;
                    a10 += p[ky + 1][kx]     * w;
                    a11 += p[ky + 1][kx + 1] * w;
                }
            a00 = fmaxf(a00, 0.f); a01 = fmaxf(a01, 0.f);
            a10 = fmaxf(a10, 0.f); a11 = fmaxf(a11, 0.f);
            h1[c][py][px] = fmaxf(fmaxf(a00, a01), fmaxf(a10, a11));
        }
    }
    __syncthreads();

    short* outr = act1 + (size_t)b * KP1;

    // ---- conv2 + relu + 2x2 pool -> act1 row (f16)
    // threads 0..249: o = t/25; 25 lanes x 7 steps cover 169 spatial.
    // i-outer so each input channel's 25 weights sit in registers.
    if (t < 250) {
        const int o = t / 25, j = t % 25;
        const float bias = cb2[o];
        float acc[7][4];
        #pragma unroll
        for (int s = 0; s < 7; ++s) {
            acc[s][0] = bias; acc[s][1] = bias; acc[s][2] = bias; acc[s][3] = bias;
        }
        for (int i = 0; i < 5; ++i) {
            float wr[25];
            #pragma unroll
            for (int kk = 0; kk < 25; ++kk) wr[kk] = cw2[(o * 5 + i) * 25 + kk];
            #pragma unroll
            for (int s = 0; s < 7; ++s) {
                const int r0 = s * 25 + j;
                const int r  = (r0 < 169) ? r0 : 168;   // clamp; discarded at store
                const int py = r / 13, px = r % 13;
                const int y0 = py * 2, x0 = px * 2;
                float p[6][6];
                #pragma unroll
                for (int ky = 0; ky < 6; ++ky) {
                    const float2* ip = (const float2*)&h1[i][y0 + ky][x0];
                    const float2 v0 = ip[0], v1 = ip[1], v2 = ip[2];
                    p[ky][0] = v0.x; p[ky][1] = v0.y; p[ky][2] = v1.x;
                    p[ky][3] = v1.y; p[ky][4] = v2.x; p[ky][5] = v2.y;
                }
                #pragma unroll
                for (int ky = 0; ky < 5; ++ky)
                    #pragma unroll
                    for (int kx = 0; kx < 5; ++kx) {
                        const float w = wr[ky * 5 + kx];
                        acc[s][0] += p[ky][kx]     * w;
                        acc[s][1] += p[ky][kx + 1] * w;
                        acc[s][2] += p[ky + 1][kx]     * w;
                        acc[s][3] += p[ky + 1][kx + 1] * w;
                    }
            }
        }
        #pragma unroll
        for (int s = 0; s < 7; ++s) {
            const int r = s * 25 + j;
            if (r < 169) {
                const float a00 = fmaxf(acc[s][0], 0.f), a01 = fmaxf(acc[s][1], 0.f);
                const float a10 = fmaxf(acc[s][2], 0.f), a11 = fmaxf(acc[s][3], 0.f);
                outr[o * 169 + r] = f2h(fmaxf(fmaxf(a00, a01), fmaxf(a10, a11)));
            }
        }
    }
    if (t < DSD)           outr[1690 + t] = f2h(x[(size_t)b * XW + t]);
    if (t >= DSD && t < 6) outr[1690 + t] = 0;   // zero pad 1693..1695
}

// ---------------------------------------------------------------------------
// Kernel 2: MFMA fp16 GEMM  C[M,N] = [relu](A[M,Kp]f16 @ W[N,Kp]f16^T + bias)
// 64x64 tile, 4 waves (each 32x32 = 2x2 frags of 16x16x32), BK=32.
// LDS rows padded to 40 shorts (80 B) -> 2-way bank aliasing only (free).
// ---------------------------------------------------------------------------
template <int RELU, int OUTH>
__global__ __launch_bounds__(256) void mfma_fc(
    const short* __restrict__ A,     // [M][Kp] f16
    const short* __restrict__ W,     // [N][Kp] f16
    const float* __restrict__ bias,  // [N]
    void* __restrict__ Cout,         // [M][N] f16 (OUTH) or f32
    int N, int Kp)
{
    __shared__ __align__(16) short As[64][40];
    __shared__ __align__(16) short Ws[64][40];

    const int tid  = threadIdx.x;
    const int m0   = blockIdx.y * 64;
    const int n0   = blockIdx.x * 64;
    const int wv   = tid >> 6, lane = tid & 63;
    const int rm   = (wv >> 1) * 32, rn = (wv & 1) * 32;
    const int lr   = lane & 15, kg = lane >> 4;
    const int sr   = tid >> 2, sc = (tid & 3) * 8;   // staging: row, col (shorts)

    f32x4 acc[2][2];
    #pragma unroll
    for (int i = 0; i < 2; ++i)
        #pragma unroll
        for (int j = 0; j < 2; ++j)
            #pragma unroll
            for (int q = 0; q < 4; ++q) acc[i][j][q] = 0.f;

    for (int k0 = 0; k0 < Kp; k0 += 32) {
        *(uint4*)&As[sr][sc] = *(const uint4*)&A[(size_t)(m0 + sr) * Kp + k0 + sc];
        *(uint4*)&Ws[sr][sc] = *(const uint4*)&W[(size_t)(n0 + sr) * Kp + k0 + sc];
        __syncthreads();
        f16x8 aF[2], bF[2];
        #pragma unroll
        for (int mi = 0; mi < 2; ++mi) aF[mi] = *(const f16x8*)&As[rm + mi * 16 + lr][kg * 8];
        #pragma unroll
        for (int nj = 0; nj < 2; ++nj) bF[nj] = *(const f16x8*)&Ws[rn + nj * 16 + lr][kg * 8];
        #pragma unroll
        for (int mi = 0; mi < 2; ++mi)
            #pragma unroll
            for (int nj = 0; nj < 2; ++nj)
                acc[mi][nj] = __builtin_amdgcn_mfma_f32_16x16x32_f16(
                    aF[mi], bF[nj], acc[mi][nj], 0, 0, 0);
        __syncthreads();
    }

    // C/D layout: col = lane&15, row = (lane>>4)*4 + q   [m89-verified]
    #pragma unroll
    for (int mi = 0; mi < 2; ++mi)
        #pragma unroll
        for (int nj = 0; nj < 2; ++nj) {
            const int col  = n0 + rn + nj * 16 + lr;
            const int rowb = m0 + rm + mi * 16 + kg * 4;
            const float bv = bias[col];
            #pragma unroll
            for (int q = 0; q < 4; ++q) {
                float v = acc[mi][nj][q] + bv;
                if (RELU) v = fmaxf(v, 0.f);
                if (OUTH) ((short*)Cout)[(size_t)(rowb + q) * N + col] = f2h(v);
                else      ((float*)Cout)[(size_t)(rowb + q) * N + col] = v;
            }
        }
}

// ---------------------------------------------------------------------------
// Kernel 3: f32 GEMM for the small tail layers (fc3, fc4)
// ---------------------------------------------------------------------------
template <int RELU>
__global__ __launch_bounds__(256) void gemm_relu(
    const float* __restrict__ A, const float* __restrict__ W,
    const float* __restrict__ bias, float* __restrict__ C,
    int M, int N, int K)
{
    constexpr int BM = 64, BN = 64, BK = 16;
    __shared__ float As[BK][BM + 1];
    __shared__ float Ws[BK][BN + 1];

    const int tid = threadIdx.x;
    const int tx = tid % 16, ty = tid / 16;
    const int m0 = blockIdx.y * BM;
    const int n0 = blockIdx.x * BN;

    float acc[4][4] = {};

    for (int k0 = 0; k0 < K; k0 += BK) {
        for (int i = tid; i < BM * BK; i += 256) {
            const int mm = i / BK, kk = i % BK;
            As[kk][mm] = A[(size_t)(m0 + mm) * K + k0 + kk];
        }
        for (int i = tid; i < BN * BK; i += 256) {
            const int nn = i / BK, kk = i % BK;
            Ws[kk][nn] = W[(size_t)(n0 + nn) * K + k0 + kk];
        }
        __syncthreads();
        #pragma unroll
        for (int kk = 0; kk < BK; ++kk) {
            float a[4], w[4];
            #pragma unroll
            for (int i = 0; i < 4; ++i) a[i] = As[kk][ty * 4 + i];
            #pragma unroll
            for (int j = 0; j < 4; ++j) w[j] = Ws[kk][tx * 4 + j];
            #pragma unroll
            for (int i = 0; i < 4; ++i)
                #pragma unroll
                for (int j = 0; j < 4; ++j)
                    acc[i][j] += a[i] * w[j];
        }
        __syncthreads();
    }

    #pragma unroll
    for (int i = 0; i < 4; ++i) {
        const int m = m0 + ty * 4 + i;
        #pragma unroll
        for (int j = 0; j < 4; ++j) {
            const int n = n0 + tx * 4 + j;
            float v = acc[i][j] + bias[n];
            if (RELU) v = fmaxf(v, 0.f);
            C[(size_t)m * N + n] = v;
        }
    }
}

// ---------------------------------------------------------------------------
// Kernel 4: fc5 + softmax + expert combine -> out[B,3]
// ---------------------------------------------------------------------------
__global__ __launch_bounds__(256) void head_kernel(
    const float* __restrict__ act5, const float* __restrict__ w5,
    const float* __restrict__ b5, const float* __restrict__ Bm,
    const float* __restrict__ Cm, const float* __restrict__ x,
    const float* __restrict__ x_tar, float* __restrict__ out)
{
    __shared__ float sw[16 * 64];
    __shared__ float sb[16];
    __shared__ float sA[16 * 9];
    __shared__ float st[3];
    const int t = threadIdx.x;
    for (int i = t; i < 1024; i += 256) sw[i] = w5[i];
    if (t < 16)  sb[t] = b5[t];
    if (t < 144) sA[t] = Bm[t] + Cm[t];
    if (t < 3)   st[t] = x_tar[t];
    __syncthreads();

    const int b = blockIdx.x * 256 + t;
    float h[64];
    const float* ar = act5 + (size_t)b * 64;
    #pragma unroll
    for (int i = 0; i < 64; ++i) h[i] = ar[i];

    float logit[16];
    float mx = -1e30f;
    #pragma unroll
    for (int n = 0; n < 16; ++n) {
        float s = sb[n];
        const float* wr = sw + n * 64;
        #pragma unroll
        for (int i = 0; i < 64; ++i) s += h[i] * wr[i];
        logit[n] = s;
        mx = fmaxf(mx, s);
    }
    float sum = 0.f;
    #pragma unroll
    for (int n = 0; n < 16; ++n) { logit[n] = __expf(logit[n] - mx); sum += logit[n]; }
    const float inv = 1.f / sum;

    const float d0 = st[0] - x[(size_t)b * XW + 0];
    const float d1 = st[1] - x[(size_t)b * XW + 1];
    const float d2 = st[2] - x[(size_t)b * XW + 2];
    float s0 = 0.f, s1 = 0.f, s2 = 0.f;
    #pragma unroll
    for (int n = 0; n < 16; ++n) {
        const float w = logit[n] * inv;
        const float* An = sA + n * 9;
        s0 += w * (An[0] * d0 + An[1] * d1 + An[2] * d2);
        s1 += w * (An[3] * d0 + An[4] * d1 + An[5] * d2);
        s2 += w * (An[6] * d0 + An[7] * d1 + An[8] * d2);
    }
    out[(size_t)b * 3 + 0] = s0;
    out[(size_t)b * 3 + 1] = s1;
    out[(size_t)b * 3 + 2] = s2;
}

// ---------------------------------------------------------------------------
extern "C" void kernel_launch(void* const* d_in, const int* in_sizes, int n_in,
                              void* d_out, int out_size, void* d_ws, size_t ws_size,
                              hipStream_t stream) {
    const float* x       = (const float*)d_in[0];
    const float* conv1_w = (const float*)d_in[1];
    const float* conv1_b = (const float*)d_in[2];
    const float* conv2_w = (const float*)d_in[3];
    const float* conv2_b = (const float*)d_in[4];
    const float* fc1_w   = (const float*)d_in[5];
    const float* fc1_b   = (const float*)d_in[6];
    const float* fc2_w   = (const float*)d_in[7];
    const float* fc2_b   = (const float*)d_in[8];
    const float* fc3_w   = (const float*)d_in[9];
    const float* fc3_b   = (const float*)d_in[10];
    const float* fc4_w   = (const float*)d_in[11];
    const float* fc4_b   = (const float*)d_in[12];
    const float* fc5_w   = (const float*)d_in[13];
    const float* fc5_b   = (const float*)d_in[14];
    const float* B_mats  = (const float*)d_in[15];
    const float* C_mats  = (const float*)d_in[16];
    const float* x_tar   = (const float*)d_in[17];
    float* out = (float*)d_out;

    char* p = (char*)d_ws;
    short* act1 = (short*)p;  p += (size_t)BSZ * KP1 * 2;   // f16 [8192][1696]
    short* act2 = (short*)p;  p += (size_t)BSZ * 512 * 2;   // f16 [8192][512]
    float* act3 = (float*)p;  p += (size_t)BSZ * 256 * 4;   // f32 [8192][256]
    float* act4 = (float*)p;  p += (size_t)BSZ * 128 * 4;   // f32 [8192][128]
    float* act5 = (float*)p;  p += (size_t)BSZ * 64 * 4;    // f32 [8192][64]
    short* w1h  = (short*)p;  p += (size_t)512 * KP1 * 2;   // f16 [512][1696]
    short* w2h  = (short*)p;  p += (size_t)256 * 512 * 2;   // f16 [256][512]

    cvt_f16_pad<<<1024, 256, 0, stream>>>(fc1_w, w1h, 512, 1693, KP1);
    cvt_f16_pad<<<256,  256, 0, stream>>>(fc2_w, w2h, 256, 512, 512);

    conv_fused<<<BSZ, 256, 0, stream>>>(x, conv1_w, conv1_b, conv2_w, conv2_b, act1);

    mfma_fc<1, 1><<<dim3(512 / 64, BSZ / 64), 256, 0, stream>>>(act1, w1h, fc1_b, act2, 512, KP1);
    mfma_fc<1, 0><<<dim3(256 / 64, BSZ / 64), 256, 0, stream>>>(act2, w2h, fc2_b, act3, 256, 512);

    gemm_relu<1><<<dim3(128 / 64, BSZ / 64), 256, 0, stream>>>(act3, fc3_w, fc3_b, act4, BSZ, 128, 256);
    gemm_relu<1><<<dim3(64 / 64,  BSZ / 64), 256, 0, stream>>>(act4, fc4_w, fc4_b, act5, BSZ, 64, 128);

    head_kernel<<<BSZ / 256, 256, 0, stream>>>(act5, fc5_w, fc5_b, B_mats, C_mats, x, x_tar, out);
}

// Round 3
// 401.549 us; speedup vs baseline: 2.7575x; 1.6835x over previous
//
#include <hip/hip_runtime.h>
#include <hip/hip_bf16.h>
#include <hip/hip_fp16.h>
#include <math.h>

#define XW 4099
#define DSD 3
#define BSZ 8192
#define KP1 1696   // fc1 K padded: 1693 -> 1696 (multiple of 32, 16B-aligned rows)

typedef __attribute__((ext_vector_type(8))) _Float16 f16x8;
typedef __attribute__((ext_vector_type(4))) float    f32x4;

static __device__ __forceinline__ short f2h(float f) {
    union { _Float16 h; short s; } u;
    u.h = (_Float16)f;
    return u.s;
}

// ---------------------------------------------------------------------------
// Kernel 0: f32 -> f16 weight conversion with K-padding.  dst[N][Kp]
// ---------------------------------------------------------------------------
__global__ __launch_bounds__(256) void cvt_f16_pad(
    const float* __restrict__ src, short* __restrict__ dst,
    int N, int K, int Kp)
{
    const int tot = N * Kp;
    for (int i = blockIdx.x * 256 + threadIdx.x; i < tot; i += gridDim.x * 256) {
        const int n = i / Kp, k = i % Kp;
        dst[i] = (k < K) ? f2h(src[(size_t)n * K + k]) : (short)0;
    }
}

// ---------------------------------------------------------------------------
// Kernel 1: fused conv1+relu+pool -> conv2+relu+pool -> act1[b][1696] (f16)
// One block per image. Per-thread 2x2-POOLED register tile (4x4 conv region,
// 8x8 f32 patch via 16 ds_read_b128). Patch loaded once, reused across all
// output channels. img/h1 rows padded so consecutive rows rotate banks.
// ---------------------------------------------------------------------------
__global__ __launch_bounds__(256, 3) void conv_fused(
    const float* __restrict__ x,
    const float* __restrict__ w1, const float* __restrict__ b1,
    const float* __restrict__ w2, const float* __restrict__ b2,
    short* __restrict__ act1)
{
    __shared__ __align__(16) float img[64][68];     // 272B row = +4 banks/row
    __shared__ __align__(16) float h1[5][32][36];   // 144B row = +4 banks/row
    __shared__ float cw1[125], cw2[1250];
    __shared__ float cb1[5], cb2[10];

    const int b = blockIdx.x;
    const int t = threadIdx.x;

    const float* xr = x + (size_t)b * XW + DSD;
    for (int idx = t; idx < 4096; idx += 256) img[idx >> 6][idx & 63] = xr[idx];
    for (int i = t; i < 125;  i += 256) cw1[i] = w1[i];
    for (int i = t; i < 1250; i += 256) cw2[i] = w2[i];
    if (t < 5)  cb1[t] = b1[t];
    if (t < 10) cb2[t] = b2[t];
    __syncthreads();

    // ---- conv1 + relu + pool: 15x15 tiles of 2x2 pooled, 225 threads
    if (t < 225) {
        const int ty = t / 15, tx = t % 15;
        const int y0 = 4 * ty, x0 = 4 * tx;
        float p[8][8];
        #pragma unroll
        for (int r = 0; r < 8; ++r) {
            const f32x4 v0 = *(const f32x4*)&img[y0 + r][x0];
            const f32x4 v1 = *(const f32x4*)&img[y0 + r][x0 + 4];
            #pragma unroll
            for (int c4 = 0; c4 < 4; ++c4) { p[r][c4] = v0[c4]; p[r][4 + c4] = v1[c4]; }
        }
        #pragma unroll 1
        for (int c = 0; c < 5; ++c) {
            float w[25];
            #pragma unroll
            for (int i = 0; i < 25; ++i) w[i] = cw1[c * 25 + i];   // broadcast
            const float bias = cb1[c];
            float acc[4][4];
            #pragma unroll
            for (int cy = 0; cy < 4; ++cy)
                #pragma unroll
                for (int cx = 0; cx < 4; ++cx) acc[cy][cx] = bias;
            #pragma unroll
            for (int ky = 0; ky < 5; ++ky)
                #pragma unroll
                for (int kx = 0; kx < 5; ++kx) {
                    const float wv = w[ky * 5 + kx];
                    #pragma unroll
                    for (int cy = 0; cy < 4; ++cy)
                        #pragma unroll
                        for (int cx = 0; cx < 4; ++cx)
                            acc[cy][cx] += p[cy + ky][cx + kx] * wv;
                }
            #pragma unroll
            for (int sy = 0; sy < 2; ++sy)
                #pragma unroll
                for (int sx = 0; sx < 2; ++sx) {
                    const float m = fmaxf(
                        fmaxf(acc[2 * sy][2 * sx],     acc[2 * sy][2 * sx + 1]),
                        fmaxf(acc[2 * sy + 1][2 * sx], acc[2 * sy + 1][2 * sx + 1]));
                    h1[c][2 * ty + sy][2 * tx + sx] = fmaxf(m, 0.f);
                }
        }
    }
    __syncthreads();

    short* outr = act1 + (size_t)b * KP1;

    // ---- conv2 + relu + pool: 5 o-groups x 49 tiles (7x7 of 2x2 pooled),
    // 245 threads; each thread does channels o and o+5 off one patch load.
    if (t < 245) {
        const int o = t / 49, q = t % 49, ty = q / 7, tx = q % 7;
        const int y0 = 4 * ty, x0 = 4 * tx;
        float acc[2][4][4];
        #pragma unroll
        for (int oo = 0; oo < 2; ++oo) {
            const float bias = cb2[o + 5 * oo];
            #pragma unroll
            for (int cy = 0; cy < 4; ++cy)
                #pragma unroll
                for (int cx = 0; cx < 4; ++cx) acc[oo][cy][cx] = bias;
        }
        #pragma unroll 1
        for (int i = 0; i < 5; ++i) {
            float p[8][8];
            #pragma unroll
            for (int r = 0; r < 8; ++r) {
                const f32x4 v0 = *(const f32x4*)&h1[i][y0 + r][x0];
                const f32x4 v1 = *(const f32x4*)&h1[i][y0 + r][x0 + 4];
                #pragma unroll
                for (int c4 = 0; c4 < 4; ++c4) { p[r][c4] = v0[c4]; p[r][4 + c4] = v1[c4]; }
            }
            #pragma unroll
            for (int oo = 0; oo < 2; ++oo) {
                float w[25];
                #pragma unroll
                for (int kk = 0; kk < 25; ++kk)
                    w[kk] = cw2[((o + 5 * oo) * 5 + i) * 25 + kk];
                #pragma unroll
                for (int ky = 0; ky < 5; ++ky)
                    #pragma unroll
                    for (int kx = 0; kx < 5; ++kx) {
                        const float wv = w[ky * 5 + kx];
                        #pragma unroll
                        for (int cy = 0; cy < 4; ++cy)
                            #pragma unroll
                            for (int cx = 0; cx < 4; ++cx)
                                acc[oo][cy][cx] += p[cy + ky][cx + kx] * wv;
                    }
            }
        }
        #pragma unroll
        for (int oo = 0; oo < 2; ++oo)
            #pragma unroll
            for (int sy = 0; sy < 2; ++sy)
                #pragma unroll
                for (int sx = 0; sx < 2; ++sx) {
                    const int py = 2 * ty + sy, px = 2 * tx + sx;
                    if (py < 13 && px < 13) {
                        const float m = fmaxf(
                            fmaxf(acc[oo][2 * sy][2 * sx],     acc[oo][2 * sy][2 * sx + 1]),
                            fmaxf(acc[oo][2 * sy + 1][2 * sx], acc[oo][2 * sy + 1][2 * sx + 1]));
                        outr[(o + 5 * oo) * 169 + py * 13 + px] = f2h(fmaxf(m, 0.f));
                    }
                }
    }
    if (t < DSD)           outr[1690 + t] = f2h(x[(size_t)b * XW + t]);
    if (t >= DSD && t < 6) outr[1690 + t] = 0;   // zero pad 1693..1695
}

// ---------------------------------------------------------------------------
// Kernel 2: MFMA fp16 GEMM  C[M,N] = [relu](A[M,Kp]f16 @ W[N,Kp]f16^T + bias)
// ---------------------------------------------------------------------------
template <int RELU, int OUTH>
__global__ __launch_bounds__(256) void mfma_fc(
    const short* __restrict__ A,     // [M][Kp] f16
    const short* __restrict__ W,     // [N][Kp] f16
    const float* __restrict__ bias,  // [N]
    void* __restrict__ Cout,         // [M][N] f16 (OUTH) or f32
    int N, int Kp)
{
    __shared__ __align__(16) short As[64][40];
    __shared__ __align__(16) short Ws[64][40];

    const int tid  = threadIdx.x;
    const int m0   = blockIdx.y * 64;
    const int n0   = blockIdx.x * 64;
    const int wv   = tid >> 6, lane = tid & 63;
    const int rm   = (wv >> 1) * 32, rn = (wv & 1) * 32;
    const int lr   = lane & 15, kg = lane >> 4;
    const int sr   = tid >> 2, sc = (tid & 3) * 8;

    f32x4 acc[2][2];
    #pragma unroll
    for (int i = 0; i < 2; ++i)
        #pragma unroll
        for (int j = 0; j < 2; ++j)
            #pragma unroll
            for (int q = 0; q < 4; ++q) acc[i][j][q] = 0.f;

    for (int k0 = 0; k0 < Kp; k0 += 32) {
        *(uint4*)&As[sr][sc] = *(const uint4*)&A[(size_t)(m0 + sr) * Kp + k0 + sc];
        *(uint4*)&Ws[sr][sc] = *(const uint4*)&W[(size_t)(n0 + sr) * Kp + k0 + sc];
        __syncthreads();
        f16x8 aF[2], bF[2];
        #pragma unroll
        for (int mi = 0; mi < 2; ++mi) aF[mi] = *(const f16x8*)&As[rm + mi * 16 + lr][kg * 8];
        #pragma unroll
        for (int nj = 0; nj < 2; ++nj) bF[nj] = *(const f16x8*)&Ws[rn + nj * 16 + lr][kg * 8];
        #pragma unroll
        for (int mi = 0; mi < 2; ++mi)
            #pragma unroll
            for (int nj = 0; nj < 2; ++nj)
                acc[mi][nj] = __builtin_amdgcn_mfma_f32_16x16x32_f16(
                    aF[mi], bF[nj], acc[mi][nj], 0, 0, 0);
        __syncthreads();
    }

    #pragma unroll
    for (int mi = 0; mi < 2; ++mi)
        #pragma unroll
        for (int nj = 0; nj < 2; ++nj) {
            const int col  = n0 + rn + nj * 16 + lr;
            const int rowb = m0 + rm + mi * 16 + kg * 4;
            const float bv = bias[col];
            #pragma unroll
            for (int q = 0; q < 4; ++q) {
                float v = acc[mi][nj][q] + bv;
                if (RELU) v = fmaxf(v, 0.f);
                if (OUTH) ((short*)Cout)[(size_t)(rowb + q) * N + col] = f2h(v);
                else      ((float*)Cout)[(size_t)(rowb + q) * N + col] = v;
            }
        }
}

// ---------------------------------------------------------------------------
// Kernel 3: f32 GEMM for the small tail layers (fc3, fc4)
// ---------------------------------------------------------------------------
template <int RELU>
__global__ __launch_bounds__(256) void gemm_relu(
    const float* __restrict__ A, const float* __restrict__ W,
    const float* __restrict__ bias, float* __restrict__ C,
    int M, int N, int K)
{
    constexpr int BM = 64, BN = 64, BK = 16;
    __shared__ float As[BK][BM + 1];
    __shared__ float Ws[BK][BN + 1];

    const int tid = threadIdx.x;
    const int tx = tid % 16, ty = tid / 16;
    const int m0 = blockIdx.y * BM;
    const int n0 = blockIdx.x * BN;

    float acc[4][4] = {};

    for (int k0 = 0; k0 < K; k0 += BK) {
        for (int i = tid; i < BM * BK; i += 256) {
            const int mm = i / BK, kk = i % BK;
            As[kk][mm] = A[(size_t)(m0 + mm) * K + k0 + kk];
        }
        for (int i = tid; i < BN * BK; i += 256) {
            const int nn = i / BK, kk = i % BK;
            Ws[kk][nn] = W[(size_t)(n0 + nn) * K + k0 + kk];
        }
        __syncthreads();
        #pragma unroll
        for (int kk = 0; kk < BK; ++kk) {
            float a[4], w[4];
            #pragma unroll
            for (int i = 0; i < 4; ++i) a[i] = As[kk][ty * 4 + i];
            #pragma unroll
            for (int j = 0; j < 4; ++j) w[j] = Ws[kk][tx * 4 + j];
            #pragma unroll
            for (int i = 0; i < 4; ++i)
                #pragma unroll
                for (int j = 0; j < 4; ++j)
                    acc[i][j] += a[i] * w[j];
        }
        __syncthreads();
    }

    #pragma unroll
    for (int i = 0; i < 4; ++i) {
        const int m = m0 + ty * 4 + i;
        #pragma unroll
        for (int j = 0; j < 4; ++j) {
            const int n = n0 + tx * 4 + j;
            float v = acc[i][j] + bias[n];
            if (RELU) v = fmaxf(v, 0.f);
            C[(size_t)m * N + n] = v;
        }
    }
}

// ---------------------------------------------------------------------------
// Kernel 4: fc5 + softmax + expert combine -> out[B,3]
// ---------------------------------------------------------------------------
__global__ __launch_bounds__(256) void head_kernel(
    const float* __restrict__ act5, const float* __restrict__ w5,
    const float* __restrict__ b5, const float* __restrict__ Bm,
    const float* __restrict__ Cm, const float* __restrict__ x,
    const float* __restrict__ x_tar, float* __restrict__ out)
{
    __shared__ float sw[16 * 64];
    __shared__ float sb[16];
    __shared__ float sA[16 * 9];
    __shared__ float st[3];
    const int t = threadIdx.x;
    for (int i = t; i < 1024; i += 256) sw[i] = w5[i];
    if (t < 16)  sb[t] = b5[t];
    if (t < 144) sA[t] = Bm[t] + Cm[t];
    if (t < 3)   st[t] = x_tar[t];
    __syncthreads();

    const int b = blockIdx.x * 256 + t;
    float h[64];
    const float* ar = act5 + (size_t)b * 64;
    #pragma unroll
    for (int i = 0; i < 64; ++i) h[i] = ar[i];

    float logit[16];
    float mx = -1e30f;
    #pragma unroll
    for (int n = 0; n < 16; ++n) {
        float s = sb[n];
        const float* wr = sw + n * 64;
        #pragma unroll
        for (int i = 0; i < 64; ++i) s += h[i] * wr[i];
        logit[n] = s;
        mx = fmaxf(mx, s);
    }
    float sum = 0.f;
    #pragma unroll
    for (int n = 0; n < 16; ++n) { logit[n] = __expf(logit[n] - mx); sum += logit[n]; }
    const float inv = 1.f / sum;

    const float d0 = st[0] - x[(size_t)b * XW + 0];
    const float d1 = st[1] - x[(size_t)b * XW + 1];
    const float d2 = st[2] - x[(size_t)b * XW + 2];
    float s0 = 0.f, s1 = 0.f, s2 = 0.f;
    #pragma unroll
    for (int n = 0; n < 16; ++n) {
        const float w = logit[n] * inv;
        const float* An = sA + n * 9;
        s0 += w * (An[0] * d0 + An[1] * d1 + An[2] * d2);
        s1 += w * (An[3] * d0 + An[4] * d1 + An[5] * d2);
        s2 += w * (An[6] * d0 + An[7] * d1 + An[8] * d2);
    }
    out[(size_t)b * 3 + 0] = s0;
    out[(size_t)b * 3 + 1] = s1;
    out[(size_t)b * 3 + 2] = s2;
}

// ---------------------------------------------------------------------------
extern "C" void kernel_launch(void* const* d_in, const int* in_sizes, int n_in,
                              void* d_out, int out_size, void* d_ws, size_t ws_size,
                              hipStream_t stream) {
    const float* x       = (const float*)d_in[0];
    const float* conv1_w = (const float*)d_in[1];
    const float* conv1_b = (const float*)d_in[2];
    const float* conv2_w = (const float*)d_in[3];
    const float* conv2_b = (const float*)d_in[4];
    const float* fc1_w   = (const float*)d_in[5];
    const float* fc1_b   = (const float*)d_in[6];
    const float* fc2_w   = (const float*)d_in[7];
    const float* fc2_b   = (const float*)d_in[8];
    const float* fc3_w   = (const float*)d_in[9];
    const float* fc3_b   = (const float*)d_in[10];
    const float* fc4_w   = (const float*)d_in[11];
    const float* fc4_b   = (const float*)d_in[12];
    const float* fc5_w   = (const float*)d_in[13];
    const float* fc5_b   = (const float*)d_in[14];
    const float* B_mats  = (const float*)d_in[15];
    const float* C_mats  = (const float*)d_in[16];
    const float* x_tar   = (const float*)d_in[17];
    float* out = (float*)d_out;

    char* p = (char*)d_ws;
    short* act1 = (short*)p;  p += (size_t)BSZ * KP1 * 2;   // f16 [8192][1696]
    short* act2 = (short*)p;  p += (size_t)BSZ * 512 * 2;   // f16 [8192][512]
    float* act3 = (float*)p;  p += (size_t)BSZ * 256 * 4;   // f32 [8192][256]
    float* act4 = (float*)p;  p += (size_t)BSZ * 128 * 4;   // f32 [8192][128]
    float* act5 = (float*)p;  p += (size_t)BSZ * 64 * 4;    // f32 [8192][64]
    short* w1h  = (short*)p;  p += (size_t)512 * KP1 * 2;   // f16 [512][1696]
    short* w2h  = (short*)p;  p += (size_t)256 * 512 * 2;   // f16 [256][512]

    cvt_f16_pad<<<1024, 256, 0, stream>>>(fc1_w, w1h, 512, 1693, KP1);
    cvt_f16_pad<<<256,  256, 0, stream>>>(fc2_w, w2h, 256, 512, 512);

    conv_fused<<<BSZ, 256, 0, stream>>>(x, conv1_w, conv1_b, conv2_w, conv2_b, act1);

    mfma_fc<1, 1><<<dim3(512 / 64, BSZ / 64), 256, 0, stream>>>(act1, w1h, fc1_b, act2, 512, KP1);
    mfma_fc<1, 0><<<dim3(256 / 64, BSZ / 64), 256, 0, stream>>>(act2, w2h, fc2_b, act3, 256, 512);

    gemm_relu<1><<<dim3(128 / 64, BSZ / 64), 256, 0, stream>>>(act3, fc3_w, fc3_b, act4, BSZ, 128, 256);
    gemm_relu<1><<<dim3(64 / 64,  BSZ / 64), 256, 0, stream>>>(act4, fc4_w, fc4_b, act5, BSZ, 64, 128);

    head_kernel<<<BSZ / 256, 256, 0, stream>>>(act5, fc5_w, fc5_b, B_mats, C_mats, x, x_tar, out);
}